// Round 7
// baseline (179.122 us; speedup 1.0000x reference)
//
#include <hip/hip_runtime.h>

// ---------------------------------------------------------------------------
// MFMA conv3x3(1->64) + per-(b,och) min/max + 64-bin histogram + head.
// conv as 32x32x16 bf16 MFMA, split precision x=xh+xl, w=wh+wl:
//   conv = xh*wh + xl*wh + xh*wl.  Bias rides K-slot 15 (A=1.0, B=bias).
// A: m=lane&31, k=(lane>>5)*8+j.  B: n=lane&31.  C: col=lane&31,
//   row=(reg&3)+8*(reg>>2)+4*(lane>>5)  [learn_hip m74/m101]
// LDS tile col-major t32[col*35+row], packed {lo16|hi16} bf16 per pixel.
// R10/R11: bank-transposed hist[bin*32+och5] (lane owns bank mrow);
//   saturating-cvt binning (sc=63.984 folds upper clamp).
// Post-mortems R13-R18 (conv kernels FROZEN):
//   - MfmaUtil*dur const across variants -> all deltas are overhead.
//   - R15: drain rewrite + bin0 lane-masking: zero dur change.  hist is
//     DS-pipe bound at per-INSTRUCTION cost: 4.19M ds_add wave-instrs /
//     256 CU x ~8cyc (atomic RMW) ~= 54 us floor; measured 60.5 = +12%
//     (staging+prologue+drain).  One atomic per value is irreducible
//     (per-lane och ownership, no cross-lane aggregation; exec-masking
//     doesn't remove instruction slots).
//   - R17: u16-packed hist -> 4x conflicts; tight launch_bounds -> spills.
//   - R18: minmax och-split neutral (like R14 col-split) -> minmax is not
//     occupancy-limited; already near floor.
// R16: head K-split x16 (2000 blocks): -14 us -> head was latency-bound.
// R19 (this round): head K-split x32 (grid 125x32 = 4000 blocks, 8 iters
//   per thread) -- the only stage with proven unexhausted TLP headroom.
//   part grows to 32 slices (8 MB ws); reduce sums 32 terms.
// ---------------------------------------------------------------------------

typedef short bf16x8 __attribute__((ext_vector_type(8)));
typedef float f32x16 __attribute__((ext_vector_type(16)));

#define TPITCH 35
#define F_OUT_ 1000
#define KDIM_ 4096

__device__ __forceinline__ unsigned f2bf(float f) {   // RNE f32 -> bf16 bits
    unsigned u = __float_as_uint(f);
    return (u + 0x7FFFu + ((u >> 16) & 1u)) >> 16;
}
__device__ __forceinline__ float bf2f(unsigned h) { return __uint_as_float(h << 16); }

// pinned saturating f32->u32 (negatives -> 0; avoids C++ UB on the cast)
__device__ __forceinline__ unsigned cvt_u32_sat(float f) {
    unsigned r;
    asm volatile("v_cvt_u32_f32 %0, %1" : "=v"(r) : "v"(f));
    return r;
}

union FragU { uint4 u; bf16x8 v; };

// ---------------- pass 1: conv + min/max (och half per block) --------------
__global__ __launch_bounds__(512, 6) void conv_minmax_kernel(
    const float* __restrict__ x, const float* __restrict__ cw,
    const float* __restrict__ cb, float* __restrict__ featQ,
    float* __restrict__ mnbuf, float* __restrict__ mxbuf)
{
    __shared__ unsigned t32[256 * TPITCH];     // 35840 B
    __shared__ float red[512];                 // mn[8][32] | mx[8][32]

    const int tid = threadIdx.x;
    const int lane = tid & 63;
    const int w = __builtin_amdgcn_readfirstlane(tid >> 6);
    const int b = blockIdx.x;
    const int seg = blockIdx.y;
    const int gz = blockIdx.z;                 // och half (0/1)
    const int mrow = lane & 31;
    const int kg = lane >> 5;
    const int r0 = seg * 32;
    const int vlim = min(32, 254 - r0);
    const int och = gz * 32 + mrow;

    // zero featQ: gz=0 blocks only -> 512 x 512 = 256K floats exactly
    if (gz == 0) featQ[(seg * 64 + b) * 512 + tid] = 0.f;

    FragU bwh, bwl;
    {
        unsigned hh[8], ll[8];
#pragma unroll
        for (int j = 0; j < 8; ++j) {
            int k = kg * 8 + j, dr = k >> 2, dc = k & 3;
            float wv = (kg == 1 && j == 7) ? cb[och]
                     : ((dr < 3 && dc < 3) ? cw[och * 9 + dr * 3 + dc] : 0.f);
            unsigned h = f2bf(wv);
            hh[j] = h;
            ll[j] = f2bf(wv - bf2f(h));
        }
        bwh.u = make_uint4(hh[0] | (hh[1] << 16), hh[2] | (hh[3] << 16),
                           hh[4] | (hh[5] << 16), hh[6] | (hh[7] << 16));
        bwl.u = make_uint4(ll[0] | (ll[1] << 16), ll[2] | (ll[3] << 16),
                           ll[4] | (ll[5] << 16), ll[6] | (ll[7] << 16));
    }
    f32x16 zc;
#pragma unroll
    for (int r = 0; r < 16; ++r) zc[r] = 0.f;

    const float* xb = x + (size_t)b * 65536;
    for (int i = tid; i < TPITCH * 256; i += 512) {
        int lrow = i >> 8, col = i & 255;
        int grow = r0 + lrow;
        float v = (grow < 256) ? xb[grow * 256 + col] : 0.f;
        unsigned h = f2bf(v);
        unsigned l = f2bf(v - bf2f(h));
        t32[col * TPITCH + lrow] = (l << 16) | h;
    }
    __syncthreads();

    float mn = 3.4e38f, mx = -3.4e38f;
    const int cbase = w * 32;
    const int cend = min(cbase + 32, 254);
    const unsigned* tb = t32 + mrow + 2 * kg;
    unsigned a0 = tb[cbase * TPITCH],       r1a = tb[cbase * TPITCH + 1];
    unsigned a1 = tb[(cbase + 1) * TPITCH], r1b = tb[(cbase + 1) * TPITCH + 1];
    unsigned a2 = tb[(cbase + 2) * TPITCH], r1c = tb[(cbase + 2) * TPITCH + 1];
#pragma unroll 2
    for (int c = cbase; c < cend; ++c) {
        int cp = min(c + 3, 255);              // prefetch next col
        unsigned a3  = tb[cp * TPITCH];
        unsigned r1d = tb[cp * TPITCH + 1];
        FragU ah, al;
        ah.u = make_uint4(__builtin_amdgcn_perm(a1, a0, 0x05040100u), a2,
                          __builtin_amdgcn_perm(r1b, r1a, 0x05040100u),
                          (r1c & 0xFFFFu) | 0x3F800000u);
        al.u = make_uint4(__builtin_amdgcn_perm(a1, a0, 0x07060302u), a2 >> 16,
                          __builtin_amdgcn_perm(r1b, r1a, 0x07060302u), r1c >> 16);
        a0 = a1; a1 = a2; a2 = a3; r1a = r1b; r1b = r1c; r1c = r1d;
        f32x16 acc = __builtin_amdgcn_mfma_f32_32x32x16_bf16(ah.v, bwh.v, zc, 0, 0, 0);
        acc = __builtin_amdgcn_mfma_f32_32x32x16_bf16(al.v, bwh.v, acc, 0, 0, 0);
        acc = __builtin_amdgcn_mfma_f32_32x32x16_bf16(ah.v, bwl.v, acc, 0, 0, 0);
        if (vlim >= 32) {
#pragma unroll
            for (int r = 0; r < 16; r += 2) {           // v_min3/v_max3 chains
                mn = fminf(fminf(mn, acc[r]), acc[r + 1]);
                mx = fmaxf(fmaxf(mx, acc[r]), acc[r + 1]);
            }
        } else {
#pragma unroll
            for (int r = 0; r < 16; ++r) {
                int crow = (r & 3) + 8 * (r >> 2) + 4 * kg;
                float v = (crow < vlim) ? acc[r] : acc[0];
                mn = fminf(mn, v); mx = fmaxf(mx, v);
            }
        }
    }

    mn = fminf(mn, __shfl_xor(mn, 32, 64));
    mx = fmaxf(mx, __shfl_xor(mx, 32, 64));
    __syncthreads();
    if (lane < 32) {
        red[w * 32 + mrow] = mn;
        red[256 + w * 32 + mrow] = mx;
    }
    __syncthreads();
    if (tid < 32) {
        float a = red[tid], c = red[256 + tid];
#pragma unroll
        for (int i = 1; i < 8; ++i) {
            a = fminf(a, red[i * 32 + tid]);
            c = fmaxf(c, red[256 + i * 32 + tid]);
        }
        mnbuf[((b * 64 + gz * 32 + tid) << 3) | seg] = a;
        mxbuf[((b * 64 + gz * 32 + tid) << 3) | seg] = c;
    }
}

// -------- pass 2: conv + bank-transposed hist (gz = och half) -- FROZEN ----
__global__ __launch_bounds__(512, 6) void conv_hist_kernel(
    const float* __restrict__ x, const float* __restrict__ cw,
    const float* __restrict__ cb, float* __restrict__ featQ,
    const float* __restrict__ mnbuf, const float* __restrict__ mxbuf)
{
    __shared__ unsigned t32[256 * TPITCH];     // 35840 B
    __shared__ unsigned hist[65 * 32];         // 8320 B: hist[bin*32 + och5]

    const int tid = threadIdx.x;
    const int lane = tid & 63;
    const int w = __builtin_amdgcn_readfirstlane(tid >> 6);
    const int b = blockIdx.x;
    const int seg = blockIdx.y;
    const int gz = blockIdx.z;                 // och half (0/1)
    const int mrow = lane & 31;
    const int kg = lane >> 5;
    const int r0 = seg * 32;
    const int vlim = min(32, 254 - r0);
    const int och = gz * 32 + mrow;

    float rmn = 3.402823466e38f, rmx = -3.402823466e38f;
#pragma unroll
    for (int s = 0; s < 8; ++s) {
        rmn = fminf(rmn, mnbuf[((b * 64 + och) << 3) | s]);
        rmx = fmaxf(rmx, mxbuf[((b * 64 + och) << 3) | s]);
    }
    float lo = fmaxf(rmn, 0.f);                // relu(min) == min(relu)
    float hi = fmaxf(rmx, 0.f);
    if (hi == lo) { lo -= 1.f; hi += 1.f; }
    const float sc = 63.984f / (hi - lo);
    const float nls = -lo * sc;
    for (int i = tid; i < 65 * 32; i += 512) hist[i] = 0u;

    FragU bwh, bwl;
    {
        unsigned hh[8], ll[8];
#pragma unroll
        for (int j = 0; j < 8; ++j) {
            int k = kg * 8 + j, dr = k >> 2, dc = k & 3;
            float wv = (kg == 1 && j == 7) ? fmaf(cb[och], sc, nls)
                     : ((dr < 3 && dc < 3) ? cw[och * 9 + dr * 3 + dc] * sc : 0.f);
            unsigned h = f2bf(wv);
            hh[j] = h;
            ll[j] = f2bf(wv - bf2f(h));
        }
        bwh.u = make_uint4(hh[0] | (hh[1] << 16), hh[2] | (hh[3] << 16),
                           hh[4] | (hh[5] << 16), hh[6] | (hh[7] << 16));
        bwl.u = make_uint4(ll[0] | (ll[1] << 16), ll[2] | (ll[3] << 16),
                           ll[4] | (ll[5] << 16), ll[6] | (ll[7] << 16));
    }
    f32x16 zc;
#pragma unroll
    for (int r = 0; r < 16; ++r) zc[r] = 0.f;

    const float* xb = x + (size_t)b * 65536;
    for (int i = tid; i < TPITCH * 256; i += 512) {
        int lrow = i >> 8, col = i & 255;
        int grow = r0 + lrow;
        float v = (grow < 256) ? xb[grow * 256 + col] : 0.f;
        unsigned h = f2bf(v);
        unsigned l = f2bf(v - bf2f(h));
        t32[col * TPITCH + lrow] = (l << 16) | h;
    }
    __syncthreads();

    const int cbase = w * 32;
    const int cend = min(cbase + 32, 254);
    unsigned* hrow = hist + mrow;              // lane owns bank mrow
    const unsigned* tb = t32 + mrow + 2 * kg;
    unsigned a0 = tb[cbase * TPITCH],       r1a = tb[cbase * TPITCH + 1];
    unsigned a1 = tb[(cbase + 1) * TPITCH], r1b = tb[(cbase + 1) * TPITCH + 1];
    unsigned a2 = tb[(cbase + 2) * TPITCH], r1c = tb[(cbase + 2) * TPITCH + 1];
#pragma unroll 2
    for (int c = cbase; c < cend; ++c) {
        int cp = min(c + 3, 255);              // prefetch next col
        unsigned a3  = tb[cp * TPITCH];
        unsigned r1d = tb[cp * TPITCH + 1];
        FragU ah, al;
        ah.u = make_uint4(__builtin_amdgcn_perm(a1, a0, 0x05040100u), a2,
                          __builtin_amdgcn_perm(r1b, r1a, 0x05040100u),
                          (r1c & 0xFFFFu) | 0x3F800000u);
        al.u = make_uint4(__builtin_amdgcn_perm(a1, a0, 0x07060302u), a2 >> 16,
                          __builtin_amdgcn_perm(r1b, r1a, 0x07060302u), r1c >> 16);
        a0 = a1; a1 = a2; a2 = a3; r1a = r1b; r1b = r1c; r1c = r1d;
        f32x16 acc = __builtin_amdgcn_mfma_f32_32x32x16_bf16(ah.v, bwh.v, zc, 0, 0, 0);
        acc = __builtin_amdgcn_mfma_f32_32x32x16_bf16(al.v, bwh.v, acc, 0, 0, 0);
        acc = __builtin_amdgcn_mfma_f32_32x32x16_bf16(ah.v, bwl.v, acc, 0, 0, 0);
        if (vlim >= 32) {
#pragma unroll
            for (int r = 0; r < 16; ++r) {
                unsigned bin = cvt_u32_sat(acc[r]);   // neg->0; t<64 by scale
                atomicAdd(&hrow[bin << 5], 1u);
            }
        } else {
#pragma unroll
            for (int r = 0; r < 16; ++r) {
                int crow = (r & 3) + 8 * (r >> 2) + 4 * kg;
                unsigned bin = cvt_u32_sat(acc[r]);
                if (crow >= vlim) bin = 64u;          // trash row
                atomicAdd(&hrow[bin << 5], 1u);
            }
        }
    }
    __syncthreads();

    for (int i = tid; i < 2048; i += 512) {
        int o = i >> 6, bin = i & 63;
        float cnt = (float)hist[(bin << 5) + o];
        int k = ((gz * 32 + o) << 6) | bin;
        atomicAdd(&featQ[((k >> 2) << 8) | (b << 2) | (k & 3)], cnt);
    }
}

// ---------------------------------------------------------------------------
// Head stage 1: partial GEMM. Grid (125 n-groups, 32 K-slices) = 4000 blocks
// of 256 threads (4 waves); per-thread loop 8 iters.  Latency-bound stage:
// more TLP each split (R12 x4, R16 x16 both paid).
// Block: 8 n-cols x K-slice(128); 4 waves split the slice (32 k each).
// ---------------------------------------------------------------------------
__global__ __launch_bounds__(256) void head_kernel(
    const float* __restrict__ featQ, const float* __restrict__ hw,
    float* __restrict__ part)
{
    __shared__ float red[4][8][64];
    const int tid = threadIdx.x;
    const int m = tid & 63;
    const int kh = __builtin_amdgcn_readfirstlane(tid >> 6);   // wave 0..3
    const int n0 = blockIdx.x * 8;
    const int q = blockIdx.y;                                  // K 32nd
    const int kqbase = q * 32 + kh * 8;                        // k-quad base
    const float* fb = featQ + kqbase * 256 + (m << 2);
    const float* wp[8];
#pragma unroll
    for (int c = 0; c < 8; ++c)
        wp[c] = hw + (size_t)(n0 + c) * KDIM_ + (kqbase << 2);

    float a[8] = {0.f, 0.f, 0.f, 0.f, 0.f, 0.f, 0.f, 0.f};
#pragma unroll 2
    for (int kq = 0; kq < 8; ++kq) {
        float4 f = *(const float4*)(fb + (kq << 8));
#pragma unroll
        for (int c = 0; c < 8; ++c) {
            float4 u = *(const float4*)(wp[c] + (kq << 2));
            a[c] += f.x * u.x + f.y * u.y + f.z * u.z + f.w * u.w;
        }
    }
#pragma unroll
    for (int c = 0; c < 8; ++c) red[kh][c][m] = a[c];
    __syncthreads();
    for (int s = tid; s < 512; s += 256) {
        int c = s >> 6, mm = s & 63;
        float v = red[0][c][mm] + red[1][c][mm] + red[2][c][mm] + red[3][c][mm];
        part[(size_t)q * 64000 + (n0 + c) * 64 + mm] = v;
    }
}

// Head stage 2: out[m][n] = hb[n] + sum_q part[q][n*64+m].  64000 elems.
__global__ __launch_bounds__(256) void head_reduce_kernel(
    const float* __restrict__ part, const float* __restrict__ hb,
    float* __restrict__ out)
{
    int idx = blockIdx.x * 256 + threadIdx.x;   // 250 blocks x 256 = 64000
    int n = idx >> 6, m = idx & 63;
    float v = hb[n];
#pragma unroll
    for (int q = 0; q < 32; ++q) v += part[q * 64000 + idx];
    out[(size_t)m * F_OUT_ + n] = v;
}

extern "C" void kernel_launch(void* const* d_in, const int* in_sizes, int n_in,
                              void* d_out, int out_size, void* d_ws, size_t ws_size,
                              hipStream_t stream) {
    const float* x      = (const float*)d_in[0];
    const float* conv_w = (const float*)d_in[1];
    const float* conv_b = (const float*)d_in[2];
    const float* head_w = (const float*)d_in[3];
    const float* head_b = (const float*)d_in[4];
    float* out   = (float*)d_out;
    float* featQ = (float*)d_ws;                 // 262144 floats (1 MB)
    float* mnbuf = featQ + 262144;               // 64*64*8
    float* mxbuf = mnbuf + 32768;
    float* part  = mxbuf + 32768;                // 32*64000 floats (8 MB)

    dim3 g1(64, 8, 2);
    dim3 g2(64, 8, 2);
    conv_minmax_kernel<<<g1, 512, 0, stream>>>(x, conv_w, conv_b, featQ, mnbuf, mxbuf);
    conv_hist_kernel<<<g2, 512, 0, stream>>>(x, conv_w, conv_b, featQ, mnbuf, mxbuf);
    head_kernel<<<dim3(125, 32), 256, 0, stream>>>(featQ, head_w, part);
    head_reduce_kernel<<<250, 256, 0, stream>>>(part, head_b, out);
}

// Round 10
// 176.503 us; speedup vs baseline: 1.0148x; 1.0148x over previous
//
#include <hip/hip_runtime.h>

// ---------------------------------------------------------------------------
// MFMA conv3x3(1->64) + per-(b,och) min/max + 64-bin histogram + head.
// conv as 32x32x16 bf16 MFMA, split precision x=xh+xl, w=wh+wl:
//   conv = xh*wh + xl*wh + xh*wl.  Bias rides K-slot 15 (A=1.0, B=bias).
// A: m=lane&31, k=(lane>>5)*8+j.  B: n=lane&31.  C: col=lane&31,
//   row=(reg&3)+8*(reg>>2)+4*(lane>>5)  [learn_hip m74/m101]
// LDS tile col-major t32[col*35+row], packed {lo16|hi16} bf16 per pixel.
// R10/R11: bank-transposed hist[bin*32+och5] (lane owns bank mrow);
//   saturating-cvt binning (sc=63.984 folds upper clamp).
// Post-mortems R13-R21 (conv kernels FROZEN at round-4/R16 form):
//   - hist: DS-pipe bound at per-INSTRUCTION cost (4096 ds_add wave-instrs
//     per block ~= 55 us chip floor; R15 lane-masking decisive: no change).
//     LDS repacks (R17) and splits (R13/R14) all regressed.  Frozen.
//   - minmax: och/col/occupancy splits all neutral -> at floor.  Frozen.
//   - head: K-split x16 paid (-14 us); x32 neutral -> floor at x16.
//   - R20 cooperative fusion failed; abandoned.
//   - R21 BUG (not a concept failure): head drain wrote only 256/512
//     results per block (single-iteration body, mm capped at 31) ->
//     absmax == max|ref| where rows 32-63 got zero.  Concept retained.
// R22 (this round): R21 with the drain loop fixed -- two passes cover all
//   512 (c,mm); mapping c=s&7, mm=s>>3 keeps 8 consecutive lanes on one
//   out cache line (8 coalesced segments/wave vs 64 for the R16 mapping).
//   Head atomicAdds directly into out (harness memsets out before launch);
//   q==0 adds bias once.  Deletes part round-trip + reduce kernel + launch.
// ---------------------------------------------------------------------------

typedef short bf16x8 __attribute__((ext_vector_type(8)));
typedef float f32x16 __attribute__((ext_vector_type(16)));

#define TPITCH 35
#define F_OUT_ 1000
#define KDIM_ 4096

__device__ __forceinline__ unsigned f2bf(float f) {   // RNE f32 -> bf16 bits
    unsigned u = __float_as_uint(f);
    return (u + 0x7FFFu + ((u >> 16) & 1u)) >> 16;
}
__device__ __forceinline__ float bf2f(unsigned h) { return __uint_as_float(h << 16); }

// pinned saturating f32->u32 (negatives -> 0; avoids C++ UB on the cast)
__device__ __forceinline__ unsigned cvt_u32_sat(float f) {
    unsigned r;
    asm volatile("v_cvt_u32_f32 %0, %1" : "=v"(r) : "v"(f));
    return r;
}

union FragU { uint4 u; bf16x8 v; };

// ---------------- pass 1: conv + min/max ------------------------
__global__ __launch_bounds__(512, 6) void conv_minmax_kernel(
    const float* __restrict__ x, const float* __restrict__ cw,
    const float* __restrict__ cb, float* __restrict__ featQ,
    float* __restrict__ mnbuf, float* __restrict__ mxbuf)
{
    __shared__ unsigned t32[256 * TPITCH];     // 35840 B
    __shared__ float red[1024];                // wmn[8][64] | wmx[8][64]

    const int tid = threadIdx.x;
    const int lane = tid & 63;
    const int w = __builtin_amdgcn_readfirstlane(tid >> 6);
    const int b = blockIdx.x;
    const int seg = blockIdx.y;
    const int mrow = lane & 31;
    const int kg = lane >> 5;
    const int r0 = seg * 32;
    const int vlim = min(32, 254 - r0);

    // zero featQ: 512 blocks x 512 = 256K floats exactly
    featQ[(seg * 64 + b) * 512 + tid] = 0.f;

    FragU bwh[2], bwl[2];
#pragma unroll
    for (int g = 0; g < 2; ++g) {
        int och = g * 32 + mrow;
        unsigned hh[8], ll[8];
#pragma unroll
        for (int j = 0; j < 8; ++j) {
            int k = kg * 8 + j, dr = k >> 2, dc = k & 3;
            float wv = (kg == 1 && j == 7) ? cb[och]
                     : ((dr < 3 && dc < 3) ? cw[och * 9 + dr * 3 + dc] : 0.f);
            unsigned h = f2bf(wv);
            hh[j] = h;
            ll[j] = f2bf(wv - bf2f(h));
        }
        bwh[g].u = make_uint4(hh[0] | (hh[1] << 16), hh[2] | (hh[3] << 16),
                              hh[4] | (hh[5] << 16), hh[6] | (hh[7] << 16));
        bwl[g].u = make_uint4(ll[0] | (ll[1] << 16), ll[2] | (ll[3] << 16),
                              ll[4] | (ll[5] << 16), ll[6] | (ll[7] << 16));
    }
    f32x16 zc;
#pragma unroll
    for (int r = 0; r < 16; ++r) zc[r] = 0.f;

    const float* xb = x + (size_t)b * 65536;
    for (int i = tid; i < TPITCH * 256; i += 512) {
        int lrow = i >> 8, col = i & 255;
        int grow = r0 + lrow;
        float v = (grow < 256) ? xb[grow * 256 + col] : 0.f;
        unsigned h = f2bf(v);
        unsigned l = f2bf(v - bf2f(h));
        t32[col * TPITCH + lrow] = (l << 16) | h;
    }
    __syncthreads();

    float mnA = 3.4e38f, mxA = -3.4e38f;
    float mnB = 3.4e38f, mxB = -3.4e38f;
    const int cbase = w * 32;
    const int cend = min(cbase + 32, 254);
    const unsigned* tb = t32 + mrow + 2 * kg;
    unsigned a0 = tb[cbase * TPITCH],       r1a = tb[cbase * TPITCH + 1];
    unsigned a1 = tb[(cbase + 1) * TPITCH], r1b = tb[(cbase + 1) * TPITCH + 1];
    unsigned a2 = tb[(cbase + 2) * TPITCH], r1c = tb[(cbase + 2) * TPITCH + 1];
#pragma unroll 2
    for (int c = cbase; c < cend; ++c) {
        int cp = min(c + 3, 255);              // prefetch next col
        unsigned a3  = tb[cp * TPITCH];
        unsigned r1d = tb[cp * TPITCH + 1];
        FragU ah, al;
        ah.u = make_uint4(__builtin_amdgcn_perm(a1, a0, 0x05040100u), a2,
                          __builtin_amdgcn_perm(r1b, r1a, 0x05040100u),
                          (r1c & 0xFFFFu) | 0x3F800000u);
        al.u = make_uint4(__builtin_amdgcn_perm(a1, a0, 0x07060302u), a2 >> 16,
                          __builtin_amdgcn_perm(r1b, r1a, 0x07060302u), r1c >> 16);
        a0 = a1; a1 = a2; a2 = a3; r1a = r1b; r1b = r1c; r1c = r1d;
        f32x16 accA = __builtin_amdgcn_mfma_f32_32x32x16_bf16(ah.v, bwh[0].v, zc, 0, 0, 0);
        f32x16 accB = __builtin_amdgcn_mfma_f32_32x32x16_bf16(ah.v, bwh[1].v, zc, 0, 0, 0);
        accA = __builtin_amdgcn_mfma_f32_32x32x16_bf16(al.v, bwh[0].v, accA, 0, 0, 0);
        accB = __builtin_amdgcn_mfma_f32_32x32x16_bf16(al.v, bwh[1].v, accB, 0, 0, 0);
        accA = __builtin_amdgcn_mfma_f32_32x32x16_bf16(ah.v, bwl[0].v, accA, 0, 0, 0);
        accB = __builtin_amdgcn_mfma_f32_32x32x16_bf16(ah.v, bwl[1].v, accB, 0, 0, 0);
        if (vlim >= 32) {
#pragma unroll
            for (int r = 0; r < 16; r += 2) {           // v_min3/v_max3 chains
                mnA = fminf(fminf(mnA, accA[r]), accA[r + 1]);
                mxA = fmaxf(fmaxf(mxA, accA[r]), accA[r + 1]);
                mnB = fminf(fminf(mnB, accB[r]), accB[r + 1]);
                mxB = fmaxf(fmaxf(mxB, accB[r]), accB[r + 1]);
            }
        } else {
#pragma unroll
            for (int r = 0; r < 16; ++r) {
                int crow = (r & 3) + 8 * (r >> 2) + 4 * kg;
                float vA = (crow < vlim) ? accA[r] : accA[0];
                float vB = (crow < vlim) ? accB[r] : accB[0];
                mnA = fminf(mnA, vA); mxA = fmaxf(mxA, vA);
                mnB = fminf(mnB, vB); mxB = fmaxf(mxB, vB);
            }
        }
    }

    mnA = fminf(mnA, __shfl_xor(mnA, 32, 64));
    mxA = fmaxf(mxA, __shfl_xor(mxA, 32, 64));
    mnB = fminf(mnB, __shfl_xor(mnB, 32, 64));
    mxB = fmaxf(mxB, __shfl_xor(mxB, 32, 64));
    __syncthreads();
    if (lane < 32) {
        red[w * 64 + mrow] = mnA;        red[512 + w * 64 + mrow] = mxA;
        red[w * 64 + 32 + mrow] = mnB;   red[512 + w * 64 + 32 + mrow] = mxB;
    }
    __syncthreads();
    if (tid < 64) {
        float a = red[tid], c = red[512 + tid];
#pragma unroll
        for (int i = 1; i < 8; ++i) {
            a = fminf(a, red[i * 64 + tid]);
            c = fmaxf(c, red[512 + i * 64 + tid]);
        }
        mnbuf[((b * 64 + tid) << 3) | seg] = a;
        mxbuf[((b * 64 + tid) << 3) | seg] = c;
    }
}

// -------- pass 2: conv + bank-transposed hist (gz = och half) -- FROZEN ----
__global__ __launch_bounds__(512, 6) void conv_hist_kernel(
    const float* __restrict__ x, const float* __restrict__ cw,
    const float* __restrict__ cb, float* __restrict__ featQ,
    const float* __restrict__ mnbuf, const float* __restrict__ mxbuf)
{
    __shared__ unsigned t32[256 * TPITCH];     // 35840 B
    __shared__ unsigned hist[65 * 32];         // 8320 B: hist[bin*32 + och5]

    const int tid = threadIdx.x;
    const int lane = tid & 63;
    const int w = __builtin_amdgcn_readfirstlane(tid >> 6);
    const int b = blockIdx.x;
    const int seg = blockIdx.y;
    const int gz = blockIdx.z;                 // och half (0/1)
    const int mrow = lane & 31;
    const int kg = lane >> 5;
    const int r0 = seg * 32;
    const int vlim = min(32, 254 - r0);
    const int och = gz * 32 + mrow;

    float rmn = 3.402823466e38f, rmx = -3.402823466e38f;
#pragma unroll
    for (int s = 0; s < 8; ++s) {
        rmn = fminf(rmn, mnbuf[((b * 64 + och) << 3) | s]);
        rmx = fmaxf(rmx, mxbuf[((b * 64 + och) << 3) | s]);
    }
    float lo = fmaxf(rmn, 0.f);                // relu(min) == min(relu)
    float hi = fmaxf(rmx, 0.f);
    if (hi == lo) { lo -= 1.f; hi += 1.f; }
    const float sc = 63.984f / (hi - lo);
    const float nls = -lo * sc;
    for (int i = tid; i < 65 * 32; i += 512) hist[i] = 0u;

    FragU bwh, bwl;
    {
        unsigned hh[8], ll[8];
#pragma unroll
        for (int j = 0; j < 8; ++j) {
            int k = kg * 8 + j, dr = k >> 2, dc = k & 3;
            float wv = (kg == 1 && j == 7) ? fmaf(cb[och], sc, nls)
                     : ((dr < 3 && dc < 3) ? cw[och * 9 + dr * 3 + dc] * sc : 0.f);
            unsigned h = f2bf(wv);
            hh[j] = h;
            ll[j] = f2bf(wv - bf2f(h));
        }
        bwh.u = make_uint4(hh[0] | (hh[1] << 16), hh[2] | (hh[3] << 16),
                           hh[4] | (hh[5] << 16), hh[6] | (hh[7] << 16));
        bwl.u = make_uint4(ll[0] | (ll[1] << 16), ll[2] | (ll[3] << 16),
                           ll[4] | (ll[5] << 16), ll[6] | (ll[7] << 16));
    }
    f32x16 zc;
#pragma unroll
    for (int r = 0; r < 16; ++r) zc[r] = 0.f;

    const float* xb = x + (size_t)b * 65536;
    for (int i = tid; i < TPITCH * 256; i += 512) {
        int lrow = i >> 8, col = i & 255;
        int grow = r0 + lrow;
        float v = (grow < 256) ? xb[grow * 256 + col] : 0.f;
        unsigned h = f2bf(v);
        unsigned l = f2bf(v - bf2f(h));
        t32[col * TPITCH + lrow] = (l << 16) | h;
    }
    __syncthreads();

    const int cbase = w * 32;
    const int cend = min(cbase + 32, 254);
    unsigned* hrow = hist + mrow;              // lane owns bank mrow
    const unsigned* tb = t32 + mrow + 2 * kg;
    unsigned a0 = tb[cbase * TPITCH],       r1a = tb[cbase * TPITCH + 1];
    unsigned a1 = tb[(cbase + 1) * TPITCH], r1b = tb[(cbase + 1) * TPITCH + 1];
    unsigned a2 = tb[(cbase + 2) * TPITCH], r1c = tb[(cbase + 2) * TPITCH + 1];
#pragma unroll 2
    for (int c = cbase; c < cend; ++c) {
        int cp = min(c + 3, 255);              // prefetch next col
        unsigned a3  = tb[cp * TPITCH];
        unsigned r1d = tb[cp * TPITCH + 1];
        FragU ah, al;
        ah.u = make_uint4(__builtin_amdgcn_perm(a1, a0, 0x05040100u), a2,
                          __builtin_amdgcn_perm(r1b, r1a, 0x05040100u),
                          (r1c & 0xFFFFu) | 0x3F800000u);
        al.u = make_uint4(__builtin_amdgcn_perm(a1, a0, 0x07060302u), a2 >> 16,
                          __builtin_amdgcn_perm(r1b, r1a, 0x07060302u), r1c >> 16);
        a0 = a1; a1 = a2; a2 = a3; r1a = r1b; r1b = r1c; r1c = r1d;
        f32x16 acc = __builtin_amdgcn_mfma_f32_32x32x16_bf16(ah.v, bwh.v, zc, 0, 0, 0);
        acc = __builtin_amdgcn_mfma_f32_32x32x16_bf16(al.v, bwh.v, acc, 0, 0, 0);
        acc = __builtin_amdgcn_mfma_f32_32x32x16_bf16(ah.v, bwl.v, acc, 0, 0, 0);
        if (vlim >= 32) {
#pragma unroll
            for (int r = 0; r < 16; ++r) {
                unsigned bin = cvt_u32_sat(acc[r]);   // neg->0; t<64 by scale
                atomicAdd(&hrow[bin << 5], 1u);
            }
        } else {
#pragma unroll
            for (int r = 0; r < 16; ++r) {
                int crow = (r & 3) + 8 * (r >> 2) + 4 * kg;
                unsigned bin = cvt_u32_sat(acc[r]);
                if (crow >= vlim) bin = 64u;          // trash row
                atomicAdd(&hrow[bin << 5], 1u);
            }
        }
    }
    __syncthreads();

    for (int i = tid; i < 2048; i += 512) {
        int o = i >> 6, bin = i & 63;
        float cnt = (float)hist[(bin << 5) + o];
        int k = ((gz * 32 + o) << 6) | bin;
        atomicAdd(&featQ[((k >> 2) << 8) | (b << 2) | (k & 3)], cnt);
    }
}

// ---------------------------------------------------------------------------
// Head: partial GEMM, atomicAdd directly into out (harness memsets out
// before launch).  Grid (125 n-groups, 16 K-slices) = 2000 blocks of 256
// (R16 optimum).  q==0 blocks add the bias.  Drain: two passes cover all
// 512 (c,mm); c=s&7, mm=s>>3 so 8 consecutive lanes share one out line.
// ---------------------------------------------------------------------------
__global__ __launch_bounds__(256) void head_kernel(
    const float* __restrict__ featQ, const float* __restrict__ hw,
    const float* __restrict__ hb, float* __restrict__ out)
{
    __shared__ float red[4][8][64];
    const int tid = threadIdx.x;
    const int m = tid & 63;
    const int kh = __builtin_amdgcn_readfirstlane(tid >> 6);   // wave 0..3
    const int n0 = blockIdx.x * 8;
    const int q = blockIdx.y;                                  // K 16th
    const int kqbase = q * 64 + kh * 16;                       // k-quad base
    const float* fb = featQ + kqbase * 256 + (m << 2);
    const float* wp[8];
#pragma unroll
    for (int c = 0; c < 8; ++c)
        wp[c] = hw + (size_t)(n0 + c) * KDIM_ + (kqbase << 2);

    float a[8] = {0.f, 0.f, 0.f, 0.f, 0.f, 0.f, 0.f, 0.f};
#pragma unroll 2
    for (int kq = 0; kq < 16; ++kq) {
        float4 f = *(const float4*)(fb + (kq << 8));
#pragma unroll
        for (int c = 0; c < 8; ++c) {
            float4 u = *(const float4*)(wp[c] + (kq << 2));
            a[c] += f.x * u.x + f.y * u.y + f.z * u.z + f.w * u.w;
        }
    }
#pragma unroll
    for (int c = 0; c < 8; ++c) red[kh][c][m] = a[c];
    __syncthreads();
    for (int s = tid; s < 512; s += 256) {
        int c = s & 7, mm = s >> 3;            // mm covers 0..63
        float v = red[0][c][mm] + red[1][c][mm] + red[2][c][mm] + red[3][c][mm];
        if (q == 0) v += hb[n0 + c];
        atomicAdd(&out[(size_t)mm * F_OUT_ + n0 + c], v);
    }
}

extern "C" void kernel_launch(void* const* d_in, const int* in_sizes, int n_in,
                              void* d_out, int out_size, void* d_ws, size_t ws_size,
                              hipStream_t stream) {
    const float* x      = (const float*)d_in[0];
    const float* conv_w = (const float*)d_in[1];
    const float* conv_b = (const float*)d_in[2];
    const float* head_w = (const float*)d_in[3];
    const float* head_b = (const float*)d_in[4];
    float* out   = (float*)d_out;
    float* featQ = (float*)d_ws;                 // 262144 floats (1 MB)
    float* mnbuf = featQ + 262144;               // 64*64*8
    float* mxbuf = mnbuf + 32768;

    dim3 g1(64, 8);
    dim3 g2(64, 8, 2);
    conv_minmax_kernel<<<g1, 512, 0, stream>>>(x, conv_w, conv_b, featQ, mnbuf, mxbuf);
    conv_hist_kernel<<<g2, 512, 0, stream>>>(x, conv_w, conv_b, featQ, mnbuf, mxbuf);
    head_kernel<<<dim3(125, 16), 256, 0, stream>>>(featQ, head_w, head_b, out);
}